// Round 9
// baseline (2425.151 us; speedup 1.0000x reference)
//
#include <hip/hip_runtime.h>
#include <hip/hip_bf16.h>
#include <cstdint>
#include <cstddef>

typedef __bf16 bf16;
typedef __bf16 bf16x8 __attribute__((ext_vector_type(8)));
typedef __bf16 bf16x4 __attribute__((ext_vector_type(4)));
typedef float  floatx4 __attribute__((ext_vector_type(4)));

__device__ __forceinline__ void gload_lds16(const bf16* g, bf16* l) {
    __builtin_amdgcn_global_load_lds((const __attribute__((address_space(1))) void*)g,
                                     (__attribute__((address_space(3))) void*)l, 16, 0, 0);
}

__device__ __forceinline__ floatx4 mfma16(bf16x8 a, bf16x8 b, floatx4 c) {
    return __builtin_amdgcn_mfma_f32_16x16x32_bf16(a, b, c, 0, 0, 0);
}

// ---------------------------------------------------------------------------
// GEMM: C[m,n] = sum_k A[m,k] * W[n,k] + bias[n]
// A: M x K bf16 row-major. W: N x K bf16 row-major (torch Linear weight).
// TN=128: block 128x128, 4 waves 2x2, wave tile 64x64 (acc 4x4).
// TN=64 (TALL): block 256x64, 4 waves stacked in M, wave tile 64x64 (acc 4x4).
//   v7: TALL replaces the old 128x64 block whose 64x32 wave tile had
//   MFMA:LDS-read ratio 1.33 (vs 2.0 here) — the worst LDS-throughput shape.
//   Per block-K-step: 1.05 MFLOP / 32KB LDS reads vs 0.52 MFLOP / 24KB.
// MODE 0: fp32 out. MODE 1: bf16 out.
// MODE 2 (N=2304): cols 0..767 -> Cb0 (Q), 768..1535 -> Cb1 (K),
//                  1536..2303 -> Cb2 as TRANSPOSED V: (B,H,64,S) bf16.
// Counted-vmcnt depth-2 pipeline (T4/m218): 3 LDS buffers; per iter
// `s_waitcnt vmcnt(LPS)` (waits only the OLDEST stage) + raw s_barrier,
// then issue stage(k+2), then compute. LPS = loads/stage/wave (4 or 5).
// SPLITK: kz=0 (+bias) -> Cf, kz=1 -> Cf1, summed in ln_k.
// Bijective XCD chunk swizzle for L2 locality.
// ---------------------------------------------------------------------------
template<int MODE, int TN, int SPLITK>
__global__ __launch_bounds__(256)
void gemm_bt(const bf16* __restrict__ A, const bf16* __restrict__ Bw,
             const float* __restrict__ bias0, const float* __restrict__ bias1,
             const float* __restrict__ bias2,
             float* __restrict__ Cf, float* __restrict__ Cf1,
             bf16* __restrict__ Cb0, bf16* __restrict__ Cb1,
             bf16* __restrict__ Cb2,
             int M, int N, int K)
{
    constexpr bool TALL = (TN == 64);
    constexpr int BM  = TALL ? 256 : 128;
    constexpr int NJ  = 4;                    // wave cols = 64 both layouts
    constexpr int ASZ = BM * 32;
    constexpr int BSZ = TN * 32;
    __shared__ __attribute__((aligned(16))) bf16 As[3 * ASZ];
    __shared__ __attribute__((aligned(16))) bf16 Bs[3 * BSZ];

    const int tid  = threadIdx.x;
    const int lane = tid & 63;
    const int wv   = tid >> 6;
    const int quad = lane >> 4;
    const int l16  = lane & 15;

    // XCD-aware chunk swizzle: blocks with same dispatch%8 (same XCD) get a
    // contiguous work chunk -> few A-panels + streamed B stay in that XCD's L2.
    int bx = blockIdx.x, by = blockIdx.y;
    {
        const int nwg = gridDim.x * gridDim.y;
        if ((nwg & 7) == 0) {
            int wg = by * gridDim.x + bx;
            wg = (wg & 7) * (nwg >> 3) + (wg >> 3);
            bx = wg % gridDim.x;
            by = wg / gridDim.x;
        }
    }
    const int m0 = by * BM;
    const int n0 = bx * TN;
    const int wm = TALL ? wv : (wv & 1);      // wave row band = wm*64
    const int wn = TALL ? 0  : (wv >> 1);     // wave col band = wn*64

    const int kz   = (SPLITK > 1) ? blockIdx.z : 0;
    const int Ksub = K / SPLITK;

    floatx4 acc[4][NJ] = {};

    const int srow = lane >> 2;
    const int scol = (lane & 3) * 8;
    const bf16* gA0 = A  + (size_t)(m0 + wv * 16 + srow) * K + kz * Ksub + scol;
    const bf16* gA1 = gA0 + (size_t)64 * K;
    const bf16* gA2 = gA1 + (size_t)64 * K;   // TALL only
    const bf16* gA3 = gA2 + (size_t)64 * K;   // TALL only
    const bf16* gB0 = Bw + (size_t)(n0 + wv * 16 + srow) * K + kz * Ksub + scol;
    const bf16* gB1 = gB0 + (size_t)64 * K;   // TN==128 only
    bf16* lA0 = &As[wv * 512];
    bf16* lB0 = &Bs[wv * 512];

    auto stage = [&](int k0, int bi) {
        gload_lds16(gA0 + k0, lA0 + bi * ASZ);
        gload_lds16(gA1 + k0, lA0 + 2048 + bi * ASZ);
        if (TALL) {
            gload_lds16(gA2 + k0, lA0 + 4096 + bi * ASZ);
            gload_lds16(gA3 + k0, lA0 + 6144 + bi * ASZ);
        }
        gload_lds16(gB0 + k0, lB0 + bi * BSZ);
        if (TN == 128) gload_lds16(gB1 + k0, lB0 + 2048 + bi * BSZ);
    };

    auto compute = [&](int bi) {
        const bf16* Ab = &As[bi * ASZ];
        const bf16* Bb = &Bs[bi * BSZ];
        bf16x8 af[4], bfr[NJ];
        #pragma unroll
        for (int i = 0; i < 4; ++i)
            af[i] = *(const bf16x8*)&Ab[(wm * 64 + i * 16 + l16) * 32 + quad * 8];
        #pragma unroll
        for (int j = 0; j < NJ; ++j)
            bfr[j] = *(const bf16x8*)&Bb[(wn * 64 + j * 16 + l16) * 32 + quad * 8];
        #pragma unroll
        for (int i = 0; i < 4; ++i)
            #pragma unroll
            for (int j = 0; j < NJ; ++j)
                acc[i][j] = mfma16(af[i], bfr[j], acc[i][j]);
    };

    stage(0, 0);
    stage(32, 1);          // Ksub >= 64 always (min 384)
    int cur = 0;
    int k0  = 0;
    for (; k0 < Ksub - 32; k0 += 32) {
        // wait only for the OLDEST stage (FIFO); newer stage stays in flight
        if constexpr (TALL) asm volatile("s_waitcnt vmcnt(5)" ::: "memory");
        else                asm volatile("s_waitcnt vmcnt(4)" ::: "memory");
        __builtin_amdgcn_s_barrier();
        if (k0 + 64 < Ksub) {
            int b2 = cur + 2; if (b2 >= 3) b2 -= 3;
            stage(k0 + 64, b2);
        }
        compute(cur);
        if (++cur == 3) cur = 0;
    }
    asm volatile("s_waitcnt vmcnt(0)" ::: "memory");
    __builtin_amdgcn_s_barrier();
    compute(cur);

    float* dstF = (SPLITK > 1 && kz != 0) ? Cf1 : Cf;

    #pragma unroll
    for (int i = 0; i < 4; ++i) {
        const int rbase = m0 + wm * 64 + i * 16 + quad * 4;
        #pragma unroll
        for (int j = 0; j < NJ; ++j) {
            const int col = n0 + wn * 64 + j * 16 + l16;
            if (MODE == 0) {
                const float bv = (SPLITK > 1 && kz != 0) ? 0.f : bias0[col];
                #pragma unroll
                for (int r = 0; r < 4; ++r)
                    dstF[(size_t)(rbase + r) * N + col] = acc[i][j][r] + bv;
            } else if (MODE == 1) {
                const float bv = bias0[col];
                #pragma unroll
                for (int r = 0; r < 4; ++r)
                    Cb0[(size_t)(rbase + r) * N + col] = (bf16)(acc[i][j][r] + bv);
            } else {
                const int sel = col / 768;
                const int cc  = col - sel * 768;
                if (sel < 2) {
                    bf16* dst = (sel == 0) ? Cb0 : Cb1;
                    const float bv = ((sel == 0) ? bias0 : bias1)[cc];
                    #pragma unroll
                    for (int r = 0; r < 4; ++r)
                        dst[(size_t)(rbase + r) * 768 + cc] = (bf16)(acc[i][j][r] + bv);
                } else {
                    // V transposed: VT[((b*12+h)*64 + d) * 512 + s], 4 consecutive s
                    const float bv = bias2[cc];
                    const int bb = rbase >> 9, s = rbase & 511;
                    const int h = cc >> 6, d = cc & 63;
                    bf16x4 o;
                    #pragma unroll
                    for (int r = 0; r < 4; ++r) o[r] = (bf16)(acc[i][j][r] + bv);
                    *(bf16x4*)(Cb2 + (((size_t)(bb * 12 + h) * 64 + d) * 512 + s)) = o;
                }
            }
        }
    }
}

// ---------------------------------------------------------------------------
// All-layer fp32 -> bf16 weight conversion. blockIdx.y = layer.
// 4 elements/thread (float4 load 16B/lane, bf16x4 store 8B/lane): both the
// 8-elem variant (131us, strided reads) and 4-chunk/thread variant (134us)
// regressed vs this measured-119us form. Do not touch again.
// Per-layer packing: [Wq|Wk|Wv](2304x768) [Wo](768x768) [W1](3072x768) [W2](768x3072)
// ---------------------------------------------------------------------------
__global__ __launch_bounds__(256)
void cvt_all(const float* __restrict__ Wq, const float* __restrict__ Wk,
             const float* __restrict__ Wv, const float* __restrict__ Wo,
             const float* __restrict__ W1, const float* __restrict__ W2,
             bf16* __restrict__ out)
{
    const int l = blockIdx.y;
    const size_t i = ((size_t)blockIdx.x * 256 + threadIdx.x) * 4;
    const size_t wdd = 589824, wdf = 2359296;
    const float* src;
    size_t off;
    if      (i <  589824) { src = Wq + l * wdd; off = i; }
    else if (i < 1179648) { src = Wk + l * wdd; off = i - 589824; }
    else if (i < 1769472) { src = Wv + l * wdd; off = i - 1179648; }
    else if (i < 2359296) { src = Wo + l * wdd; off = i - 1769472; }
    else if (i < 4718592) { src = W1 + l * wdf; off = i - 2359296; }
    else                  { src = W2 + l * wdf; off = i - 4718592; }
    const float4 v = *(const float4*)(src + off);
    bf16x4 o;
    o[0] = (bf16)v.x; o[1] = (bf16)v.y; o[2] = (bf16)v.z; o[3] = (bf16)v.w;
    *(bf16x4*)(out + (size_t)l * 7077888 + i) = o;
}

// ---------------------------------------------------------------------------
// Flash attention, fixed-shift softmax (exact: softmax is shift-invariant).
// Block = (64 q-rows, h, b), 4 waves; wave owns 16 q-rows.
// p = exp(s*scale + maskbias - 16); row-sum deferred to epilogue.
// K/V XOR-swizzled (linear gload_lds dest + inverse-swizzled global source
// column + swizzled read addr); K/V double-buffered, 1 barrier/iter.
// ---------------------------------------------------------------------------
__global__ __launch_bounds__(256)
void attn3(const bf16* __restrict__ Q, const bf16* __restrict__ Kb,
           const bf16* __restrict__ VT, const float* __restrict__ mask,
           bf16* __restrict__ CTX)
{
    __shared__ __attribute__((aligned(16))) bf16 Ks[2][64 * 64];   // [key][d], swizzled
    __shared__ __attribute__((aligned(16))) bf16 Vs[2][64 * 64];   // [d][key], swizzled
    __shared__ __attribute__((aligned(16))) bf16 Ps[4 * 16 * 72];
    __shared__ float mb[512];

    const int tid  = threadIdx.x;
    const int lane = tid & 63;
    const int w    = tid >> 6;
    const int quad = lane >> 4;
    const int l16  = lane & 15;
    const int qt = blockIdx.x, h = blockIdx.y, b = blockIdx.z;

    // mask bias with softmax shift folded in
    mb[tid]       = (mask[b * 512 + tid] == 0.f)       ? -1e9f : -16.0f;
    mb[tid + 256] = (mask[b * 512 + tid + 256] == 0.f) ? -1e9f : -16.0f;

    bf16x8 qf0, qf1;
    {
        const bf16* qp = Q + (size_t)(b * 512 + qt * 64 + w * 16 + l16) * 768 + h * 64;
        qf0 = *(const bf16x8*)(qp + quad * 8);
        qf1 = *(const bf16x8*)(qp + 32 + quad * 8);
    }

    float lsum[4] = {0.f, 0.f, 0.f, 0.f};
    floatx4 accO[4] = {};
    bf16* pw = &Ps[w * 1152];

    const int srow8 = lane >> 3;
    // pre-swizzled source column: LDS[row][c] will hold G[row][c ^ ((row&7)<<3)]
    const int scol8 = ((lane & 7) * 8) ^ (srow8 << 3);
    const int r0b   = w * 16;

    auto stageKV = [&](int kt, int bi) {
        #pragma unroll
        for (int i = 0; i < 2; ++i) {
            const int r0 = r0b + i * 8;   // r0 % 8 == 0, so row&7 == srow8
            gload_lds16(Kb + (size_t)(b * 512 + kt * 64 + r0 + srow8) * 768 + h * 64 + scol8,
                        &Ks[bi][r0 * 64]);
            gload_lds16(VT + ((size_t)(b * 12 + h) * 64 + r0 + srow8) * 512 + kt * 64 + scol8,
                        &Vs[bi][r0 * 64]);
        }
    };

    stageKV(0, 0);
    int cur = 0;
    const int swm = (l16 & 7) << 3;   // read-side XOR mask (elements), row&7 == l16&7

    for (int kt = 0; kt < 8; ++kt) {
        __syncthreads();                      // buf[cur] staged (barrier drains vmcnt)
        if (kt < 7) stageKV(kt + 1, cur ^ 1); // prefetch overlaps compute below

        // S tile -> p = exp(s*0.125 + mb) ; write straight to A-layout LDS
        #pragma unroll
        for (int ct = 0; ct < 4; ++ct) {
            const bf16x8 kf0 = *(const bf16x8*)&Ks[cur][(ct * 16 + l16) * 64 + ((quad * 8) ^ swm)];
            const bf16x8 kf1 = *(const bf16x8*)&Ks[cur][(ct * 16 + l16) * 64 + ((quad * 8 + 32) ^ swm)];
            floatx4 a = {0.f, 0.f, 0.f, 0.f};
            a = mfma16(qf0, kf0, a);
            a = mfma16(qf1, kf1, a);
            const float mbv = mb[kt * 64 + ct * 16 + l16];
            #pragma unroll
            for (int r = 0; r < 4; ++r) {
                const float p = __expf(fmaf(a[r], 0.125f, mbv));
                lsum[r] += p;
                pw[(quad * 4 + r) * 72 + ct * 16 + l16] = (bf16)p;
            }
        }

        #pragma unroll
        for (int kc = 0; kc < 2; ++kc) {
            const bf16x8 af = *(const bf16x8*)&pw[l16 * 72 + kc * 32 + quad * 8];
            #pragma unroll
            for (int ct2 = 0; ct2 < 4; ++ct2) {
                const bf16x8 bv = *(const bf16x8*)&Vs[cur][(ct2 * 16 + l16) * 64 + ((kc * 32 + quad * 8) ^ swm)];
                accO[ct2] = mfma16(af, bv, accO[ct2]);
            }
        }
        cur ^= 1;
    }

    // one cross-lane sum reduction at the end (lanes with same quad hold same rows)
    float inv[4];
    #pragma unroll
    for (int r = 0; r < 4; ++r) {
        float s = lsum[r];
        #pragma unroll
        for (int o = 1; o < 16; o <<= 1) s += __shfl_xor(s, o);
        inv[r] = 1.0f / s;
    }
    #pragma unroll
    for (int ct2 = 0; ct2 < 4; ++ct2)
        #pragma unroll
        for (int r = 0; r < 4; ++r) {
            const int row = qt * 64 + w * 16 + quad * 4 + r;
            CTX[(size_t)(b * 512 + row) * 768 + h * 64 + ct2 * 16 + l16] =
                (bf16)(accO[ct2][r] * inv[r]);
        }
}

// ---------------------------------------------------------------------------
__global__ __launch_bounds__(256)
void embed_ln_k(const int* __restrict__ ids, const int* __restrict__ tts,
                const float* __restrict__ we, const float* __restrict__ pe,
                const float* __restrict__ te, const float* __restrict__ g,
                const float* __restrict__ b, float* __restrict__ X,
                bf16* __restrict__ XB)
{
    __shared__ float red[4];
    const int row = blockIdx.x;
    const int s   = row & 511;
    const int tid = threadIdx.x;
    const int id  = ids[row];
    const int tt  = tts[row];
    const float* pwp = we + (size_t)id * 768;
    const float* pt = te + (size_t)tt * 768;
    const float* pp = pe + (size_t)s * 768;
    const size_t base = (size_t)row * 768;

    float v[3];
    #pragma unroll
    for (int j = 0; j < 3; ++j) {
        const int c = tid + j * 256;
        v[j] = pwp[c] + pt[c] + pp[c];
    }
    float sm = v[0] + v[1] + v[2];
    for (int o = 32; o; o >>= 1) sm += __shfl_down(sm, o);
    if ((tid & 63) == 0) red[tid >> 6] = sm;
    __syncthreads();
    const float mu = (red[0] + red[1] + red[2] + red[3]) * (1.0f / 768.0f);
    float q = 0.f;
    #pragma unroll
    for (int j = 0; j < 3; ++j) { const float d = v[j] - mu; q += d * d; }
    __syncthreads();
    for (int o = 32; o; o >>= 1) q += __shfl_down(q, o);
    if ((tid & 63) == 0) red[tid >> 6] = q;
    __syncthreads();
    const float var  = (red[0] + red[1] + red[2] + red[3]) * (1.0f / 768.0f);
    const float rstd = rsqrtf(var + 1e-12f);
    #pragma unroll
    for (int j = 0; j < 3; ++j) {
        const int c = tid + j * 256;
        const float o = (v[j] - mu) * rstd * g[c] + b[c];
        X[base + c]  = o;
        XB[base + c] = (bf16)o;
    }
}

// T2: optional second fp32 partial (split-K GEMM) summed in during load.
__global__ __launch_bounds__(256)
void ln_k(const float* T, const float* T2, const float* res,
          const float* g, const float* bta,
          float* Xo, bf16* XBo)
{
    __shared__ float red[4];
    const int row = blockIdx.x;
    const int tid = threadIdx.x;
    const size_t base = (size_t)row * 768;

    float v[3];
    #pragma unroll
    for (int j = 0; j < 3; ++j) {
        const int c = tid + j * 256;
        float x = T[base + c];
        if (T2)  x += T2[base + c];
        if (res) x += res[base + c];
        v[j] = x;
    }
    float sm = v[0] + v[1] + v[2];
    for (int o = 32; o; o >>= 1) sm += __shfl_down(sm, o);
    if ((tid & 63) == 0) red[tid >> 6] = sm;
    __syncthreads();
    const float mu = (red[0] + red[1] + red[2] + red[3]) * (1.0f / 768.0f);
    float q = 0.f;
    #pragma unroll
    for (int j = 0; j < 3; ++j) { const float d = v[j] - mu; q += d * d; }
    __syncthreads();
    for (int o = 32; o; o >>= 1) q += __shfl_down(q, o);
    if ((tid & 63) == 0) red[tid >> 6] = q;
    __syncthreads();
    const float var  = (red[0] + red[1] + red[2] + red[3]) * (1.0f / 768.0f);
    const float rstd = rsqrtf(var + 1e-5f);
    #pragma unroll
    for (int j = 0; j < 3; ++j) {
        const int c = tid + j * 256;
        const float o = (v[j] - mu) * rstd * g[c] + bta[c];
        Xo[base + c]  = o;
        XBo[base + c] = (bf16)o;
    }
}

// ---------------------------------------------------------------------------
extern "C" void kernel_launch(void* const* d_in, const int* in_sizes, int n_in,
                              void* d_out, int out_size, void* d_ws, size_t ws_size,
                              hipStream_t stream)
{
    const int*   ids  = (const int*)d_in[0];
    const int*   tts  = (const int*)d_in[1];
    const float* mask = (const float*)d_in[2];
    const float* wemb = (const float*)d_in[3];
    const float* pemb = (const float*)d_in[4];
    const float* temb = (const float*)d_in[5];
    const float* eg   = (const float*)d_in[6];
    const float* eb   = (const float*)d_in[7];
    const float* Wq   = (const float*)d_in[8];
    const float* bq   = (const float*)d_in[9];
    const float* Wk   = (const float*)d_in[10];
    const float* bk   = (const float*)d_in[11];
    const float* Wv   = (const float*)d_in[12];
    const float* bv   = (const float*)d_in[13];
    const float* Wo   = (const float*)d_in[14];
    const float* bo   = (const float*)d_in[15];
    const float* ag   = (const float*)d_in[16];
    const float* ab   = (const float*)d_in[17];
    const float* W1   = (const float*)d_in[18];
    const float* b1   = (const float*)d_in[19];
    const float* W2   = (const float*)d_in[20];
    const float* b2   = (const float*)d_in[21];
    const float* fg   = (const float*)d_in[22];
    const float* fb   = (const float*)d_in[23];

    char* p = (char*)d_ws;
    float* X   = (float*)p; p += 12582912;   // residual stream fp32
    bf16* XB   = (bf16*)p;  p += 6291456;    // bf16 of current GEMM input
    bf16* Qb   = (bf16*)p;  p += 6291456;
    bf16* Kbuf = (bf16*)p;  p += 6291456;
    bf16* CTXb = (bf16*)p;  p += 6291456;
    float* T1  = (float*)p; p += 12582912;   // fp32 GEMM out (pre-LN)
    bf16* HB   = (bf16*)p;  p += 25165824;   // FFN hidden (B,S,F) bf16
    bf16* WB   = (bf16*)p;  p += 169869312;  // all-layer bf16 weights
    bf16* VT   = HB;                         // (B,H,64,S) — lifetime disjoint from HB
    float* T1b = (float*)Qb;                 // split-K kz=1 partial: Qb+Kbuf
                                             // (12.58 MB = M*N fp32), dead during
                                             // attn-out and FFN2 GEMMs

    cvt_all<<<dim3(6912, 12), 256, 0, stream>>>(Wq, Wk, Wv, Wo, W1, W2, WB);
    embed_ln_k<<<4096, 256, 0, stream>>>(ids, tts, wemb, pemb, temb, eg, eb, X, XB);

    for (int l = 0; l < 12; ++l) {
        bf16* wb = WB + (size_t)l * 7077888;
        gemm_bt<2, 128, 1><<<dim3(18, 32), 256, 0, stream>>>(
            XB, wb, bq + l * 768, bk + l * 768, bv + l * 768,
            nullptr, nullptr, Qb, Kbuf, VT, 4096, 2304, 768);
        attn3<<<dim3(8, 12, 8), 256, 0, stream>>>(Qb, Kbuf, VT, mask, CTXb);
        // split-K=2: kz=0 (+bias) -> T1, kz=1 -> T1b; summed in ln_k
        gemm_bt<0, 64, 2><<<dim3(12, 16, 2), 256, 0, stream>>>(
            CTXb, wb + 1769472, bo + l * 768, nullptr, nullptr,
            T1, T1b, nullptr, nullptr, nullptr, 4096, 768, 768);
        ln_k<<<4096, 256, 0, stream>>>(T1, T1b, X, ag + l * 768, ab + l * 768, X, XB);
        gemm_bt<1, 128, 1><<<dim3(24, 32), 256, 0, stream>>>(
            XB, wb + 2359296, b1 + (size_t)l * 3072, nullptr, nullptr,
            nullptr, nullptr, HB, nullptr, nullptr, 4096, 3072, 768);
        gemm_bt<0, 64, 2><<<dim3(12, 16, 2), 256, 0, stream>>>(
            HB, wb + 4718592, b2 + l * 768, nullptr, nullptr,
            T1, T1b, nullptr, nullptr, nullptr, 4096, 768, 3072);
        float* outX = (l == 11) ? (float*)d_out : X;
        ln_k<<<4096, 256, 0, stream>>>(T1, T1b, nullptr, fg + l * 768, fb + l * 768, outX, XB);
    }
}

// Round 11
// 2258.760 us; speedup vs baseline: 1.0737x; 1.0737x over previous
//
#include <hip/hip_runtime.h>
#include <hip/hip_bf16.h>
#include <cstdint>
#include <cstddef>

typedef __bf16 bf16;
typedef __bf16 bf16x8 __attribute__((ext_vector_type(8)));
typedef __bf16 bf16x4 __attribute__((ext_vector_type(4)));
typedef float  floatx4 __attribute__((ext_vector_type(4)));

__device__ __forceinline__ void gload_lds16(const bf16* g, bf16* l) {
    __builtin_amdgcn_global_load_lds((const __attribute__((address_space(1))) void*)g,
                                     (__attribute__((address_space(3))) void*)l, 16, 0, 0);
}

__device__ __forceinline__ floatx4 mfma16(bf16x8 a, bf16x8 b, floatx4 c) {
    return __builtin_amdgcn_mfma_f32_16x16x32_bf16(a, b, c, 0, 0, 0);
}

// ---------------------------------------------------------------------------
// GEMM: C[m,n] = sum_k A[m,k] * W[n,k] + bias[n]
// A: M x K bf16 row-major. W: N x K bf16 row-major (torch Linear weight).
// TN=128: block 128x128, 4 waves 2x2, wave tile 64x64 (acc 4x4).
// TN=64:  block 128x64,  4 waves 2x2, wave tile 64x32 (acc 4x2).
//   [v8 NOTE: the v7 256x64 "TALL" reshape (wave 64x64, better MFMA:LDS ratio)
//    MEASURED -110us WORSE (2425 vs 2314) — occupancy 3->1.5 blocks/CU and
//    2x M-footprint lost more than the ratio gained. Do not revisit without
//    counter evidence.]
// MODE 0: fp32 out. MODE 1: bf16 out.
// MODE 2 (N=2304): cols 0..767 -> Cb0 (Q), 768..1535 -> Cb1 (K),
//                  1536..2303 -> Cb2 as TRANSPOSED V: (B,H,64,S) bf16.
// Counted-vmcnt depth-2 pipeline (T4/m218): 3 LDS buffers; per iter
// `s_waitcnt vmcnt(LPS)` (waits only the OLDEST stage; never 0 in main loop)
// + raw s_barrier, then issue stage(k+2), then compute. LPS = loads/stage
// (4 for TN=128, 3 for TN=64).
// SPLITK: kz=0 (+bias) -> Cf, kz=1 -> Cf1 (explicit ptr), summed in ln_k.
// Bijective XCD chunk swizzle for L2 locality.
// ---------------------------------------------------------------------------
template<int MODE, int TN, int SPLITK>
__global__ __launch_bounds__(256)
void gemm_bt(const bf16* __restrict__ A, const bf16* __restrict__ Bw,
             const float* __restrict__ bias0, const float* __restrict__ bias1,
             const float* __restrict__ bias2,
             float* __restrict__ Cf, float* __restrict__ Cf1,
             bf16* __restrict__ Cb0, bf16* __restrict__ Cb1,
             bf16* __restrict__ Cb2,
             int M, int N, int K)
{
    constexpr int NJ  = TN / 32;
    constexpr int ASZ = 128 * 32;
    constexpr int BSZ = TN * 32;
    __shared__ __attribute__((aligned(16))) bf16 As[3 * ASZ];
    __shared__ __attribute__((aligned(16))) bf16 Bs[3 * BSZ];

    const int tid  = threadIdx.x;
    const int lane = tid & 63;
    const int wv   = tid >> 6;
    const int quad = lane >> 4;
    const int l16  = lane & 15;

    // XCD-aware chunk swizzle: blocks with same dispatch%8 (same XCD) get a
    // contiguous work chunk -> few A-panels + streamed B stay in that XCD's L2.
    int bx = blockIdx.x, by = blockIdx.y;
    {
        const int nwg = gridDim.x * gridDim.y;
        if ((nwg & 7) == 0) {
            int wg = by * gridDim.x + bx;
            wg = (wg & 7) * (nwg >> 3) + (wg >> 3);
            bx = wg % gridDim.x;
            by = wg / gridDim.x;
        }
    }
    const int m0 = by * 128;
    const int n0 = bx * TN;
    const int wm = wv & 1;
    const int wn = wv >> 1;

    const int kz   = (SPLITK > 1) ? blockIdx.z : 0;
    const int Ksub = K / SPLITK;

    floatx4 acc[4][NJ] = {};

    const int srow = lane >> 2;
    const int scol = (lane & 3) * 8;
    const bf16* gA0 = A  + (size_t)(m0 + wv * 16 + srow) * K + kz * Ksub + scol;
    const bf16* gA1 = gA0 + (size_t)64 * K;
    const bf16* gB0 = Bw + (size_t)(n0 + wv * 16 + srow) * K + kz * Ksub + scol;
    const bf16* gB1 = gB0 + (size_t)64 * K;   // TN==128 only
    bf16* lA0 = &As[wv * 512];
    bf16* lA1 = &As[2048 + wv * 512];
    bf16* lB0 = &Bs[wv * 512];
    bf16* lB1 = &Bs[2048 + wv * 512];         // TN==128 only

    auto stage = [&](int k0, int bi) {
        gload_lds16(gA0 + k0, lA0 + bi * ASZ);
        gload_lds16(gA1 + k0, lA1 + bi * ASZ);
        gload_lds16(gB0 + k0, lB0 + bi * BSZ);
        if (TN == 128) gload_lds16(gB1 + k0, lB1 + bi * BSZ);
    };

    auto compute = [&](int bi) {
        const bf16* Ab = &As[bi * ASZ];
        const bf16* Bb = &Bs[bi * BSZ];
        bf16x8 af[4], bfr[NJ];
        #pragma unroll
        for (int i = 0; i < 4; ++i)
            af[i] = *(const bf16x8*)&Ab[(wm * 64 + i * 16 + l16) * 32 + quad * 8];
        #pragma unroll
        for (int j = 0; j < NJ; ++j)
            bfr[j] = *(const bf16x8*)&Bb[(wn * NJ * 16 + j * 16 + l16) * 32 + quad * 8];
        #pragma unroll
        for (int i = 0; i < 4; ++i)
            #pragma unroll
            for (int j = 0; j < NJ; ++j)
                acc[i][j] = mfma16(af[i], bfr[j], acc[i][j]);
    };

    stage(0, 0);
    stage(32, 1);          // Ksub >= 64 always (min 384)
    int cur = 0;
    int k0  = 0;
    for (; k0 < Ksub - 32; k0 += 32) {
        // wait only for the OLDEST stage (FIFO); newer stage stays in flight
        if constexpr (TN == 128) asm volatile("s_waitcnt vmcnt(4)" ::: "memory");
        else                     asm volatile("s_waitcnt vmcnt(3)" ::: "memory");
        __builtin_amdgcn_s_barrier();
        if (k0 + 64 < Ksub) {
            int b2 = cur + 2; if (b2 >= 3) b2 -= 3;
            stage(k0 + 64, b2);
        }
        compute(cur);
        if (++cur == 3) cur = 0;
    }
    asm volatile("s_waitcnt vmcnt(0)" ::: "memory");
    __builtin_amdgcn_s_barrier();
    compute(cur);

    float* dstF = (SPLITK > 1 && kz != 0) ? Cf1 : Cf;

    #pragma unroll
    for (int i = 0; i < 4; ++i) {
        const int rbase = m0 + wm * 64 + i * 16 + quad * 4;
        #pragma unroll
        for (int j = 0; j < NJ; ++j) {
            const int col = n0 + wn * NJ * 16 + j * 16 + l16;
            if (MODE == 0) {
                const float bv = (SPLITK > 1 && kz != 0) ? 0.f : bias0[col];
                #pragma unroll
                for (int r = 0; r < 4; ++r)
                    dstF[(size_t)(rbase + r) * N + col] = acc[i][j][r] + bv;
            } else if (MODE == 1) {
                const float bv = bias0[col];
                #pragma unroll
                for (int r = 0; r < 4; ++r)
                    Cb0[(size_t)(rbase + r) * N + col] = (bf16)(acc[i][j][r] + bv);
            } else {
                const int sel = col / 768;
                const int cc  = col - sel * 768;
                if (sel < 2) {
                    bf16* dst = (sel == 0) ? Cb0 : Cb1;
                    const float bv = ((sel == 0) ? bias0 : bias1)[cc];
                    #pragma unroll
                    for (int r = 0; r < 4; ++r)
                        dst[(size_t)(rbase + r) * 768 + cc] = (bf16)(acc[i][j][r] + bv);
                } else {
                    // V transposed: VT[((b*12+h)*64 + d) * 512 + s], 4 consecutive s
                    const float bv = bias2[cc];
                    const int bb = rbase >> 9, s = rbase & 511;
                    const int h = cc >> 6, d = cc & 63;
                    bf16x4 o;
                    #pragma unroll
                    for (int r = 0; r < 4; ++r) o[r] = (bf16)(acc[i][j][r] + bv);
                    *(bf16x4*)(Cb2 + (((size_t)(bb * 12 + h) * 64 + d) * 512 + s)) = o;
                }
            }
        }
    }
}

// ---------------------------------------------------------------------------
// Per-layer fp32 -> bf16 weight conversion (v8: split from one 82944-block
// monolith into 12 per-layer dispatches of 6912 blocks, launched just before
// each layer's QKV GEMM. Perf-neutral by construction (same bytes, same
// access pattern — the proven 119us form, 4 elem/thread); purpose is
// OBSERVABILITY: the ~120us monolith crowded every GEMM out of the rocprof
// top-5. Side benefit: converted weights are L2/L3-warm for the QKV B-fetch.
// Layer packing: [Wq|Wk|Wv](2304x768) [Wo](768x768) [W1](3072x768) [W2](768x3072)
// ---------------------------------------------------------------------------
__global__ __launch_bounds__(256)
void cvt_layer(const float* __restrict__ Wq, const float* __restrict__ Wk,
               const float* __restrict__ Wv, const float* __restrict__ Wo,
               const float* __restrict__ W1, const float* __restrict__ W2,
               bf16* __restrict__ out)
{
    const size_t i = ((size_t)blockIdx.x * 256 + threadIdx.x) * 4;
    const float* src;
    size_t off;
    if      (i <  589824) { src = Wq; off = i; }
    else if (i < 1179648) { src = Wk; off = i - 589824; }
    else if (i < 1769472) { src = Wv; off = i - 1179648; }
    else if (i < 2359296) { src = Wo; off = i - 1769472; }
    else if (i < 4718592) { src = W1; off = i - 2359296; }
    else                  { src = W2; off = i - 4718592; }
    const float4 v = *(const float4*)(src + off);
    bf16x4 o;
    o[0] = (bf16)v.x; o[1] = (bf16)v.y; o[2] = (bf16)v.z; o[3] = (bf16)v.w;
    *(bf16x4*)(out + i) = o;
}

// ---------------------------------------------------------------------------
// Flash attention, fixed-shift softmax (exact: softmax is shift-invariant).
// Block = (64 q-rows, h, b), 4 waves; wave owns 16 q-rows.
// p = exp(s*scale + maskbias - 16); row-sum deferred to epilogue.
// K/V XOR-swizzled (linear gload_lds dest + inverse-swizzled global source
// column + swizzled read addr); K/V double-buffered, 1 barrier/iter.
// ---------------------------------------------------------------------------
__global__ __launch_bounds__(256)
void attn3(const bf16* __restrict__ Q, const bf16* __restrict__ Kb,
           const bf16* __restrict__ VT, const float* __restrict__ mask,
           bf16* __restrict__ CTX)
{
    __shared__ __attribute__((aligned(16))) bf16 Ks[2][64 * 64];   // [key][d], swizzled
    __shared__ __attribute__((aligned(16))) bf16 Vs[2][64 * 64];   // [d][key], swizzled
    __shared__ __attribute__((aligned(16))) bf16 Ps[4 * 16 * 72];
    __shared__ float mb[512];

    const int tid  = threadIdx.x;
    const int lane = tid & 63;
    const int w    = tid >> 6;
    const int quad = lane >> 4;
    const int l16  = lane & 15;
    const int qt = blockIdx.x, h = blockIdx.y, b = blockIdx.z;

    // mask bias with softmax shift folded in
    mb[tid]       = (mask[b * 512 + tid] == 0.f)       ? -1e9f : -16.0f;
    mb[tid + 256] = (mask[b * 512 + tid + 256] == 0.f) ? -1e9f : -16.0f;

    bf16x8 qf0, qf1;
    {
        const bf16* qp = Q + (size_t)(b * 512 + qt * 64 + w * 16 + l16) * 768 + h * 64;
        qf0 = *(const bf16x8*)(qp + quad * 8);
        qf1 = *(const bf16x8*)(qp + 32 + quad * 8);
    }

    float lsum[4] = {0.f, 0.f, 0.f, 0.f};
    floatx4 accO[4] = {};
    bf16* pw = &Ps[w * 1152];

    const int srow8 = lane >> 3;
    // pre-swizzled source column: LDS[row][c] will hold G[row][c ^ ((row&7)<<3)]
    const int scol8 = ((lane & 7) * 8) ^ (srow8 << 3);
    const int r0b   = w * 16;

    auto stageKV = [&](int kt, int bi) {
        #pragma unroll
        for (int i = 0; i < 2; ++i) {
            const int r0 = r0b + i * 8;   // r0 % 8 == 0, so row&7 == srow8
            gload_lds16(Kb + (size_t)(b * 512 + kt * 64 + r0 + srow8) * 768 + h * 64 + scol8,
                        &Ks[bi][r0 * 64]);
            gload_lds16(VT + ((size_t)(b * 12 + h) * 64 + r0 + srow8) * 512 + kt * 64 + scol8,
                        &Vs[bi][r0 * 64]);
        }
    };

    stageKV(0, 0);
    int cur = 0;
    const int swm = (l16 & 7) << 3;   // read-side XOR mask (elements), row&7 == l16&7

    for (int kt = 0; kt < 8; ++kt) {
        __syncthreads();                      // buf[cur] staged (barrier drains vmcnt)
        if (kt < 7) stageKV(kt + 1, cur ^ 1); // prefetch overlaps compute below

        // S tile -> p = exp(s*0.125 + mb) ; write straight to A-layout LDS
        #pragma unroll
        for (int ct = 0; ct < 4; ++ct) {
            const bf16x8 kf0 = *(const bf16x8*)&Ks[cur][(ct * 16 + l16) * 64 + ((quad * 8) ^ swm)];
            const bf16x8 kf1 = *(const bf16x8*)&Ks[cur][(ct * 16 + l16) * 64 + ((quad * 8 + 32) ^ swm)];
            floatx4 a = {0.f, 0.f, 0.f, 0.f};
            a = mfma16(qf0, kf0, a);
            a = mfma16(qf1, kf1, a);
            const float mbv = mb[kt * 64 + ct * 16 + l16];
            #pragma unroll
            for (int r = 0; r < 4; ++r) {
                const float p = __expf(fmaf(a[r], 0.125f, mbv));
                lsum[r] += p;
                pw[(quad * 4 + r) * 72 + ct * 16 + l16] = (bf16)p;
            }
        }

        #pragma unroll
        for (int kc = 0; kc < 2; ++kc) {
            const bf16x8 af = *(const bf16x8*)&pw[l16 * 72 + kc * 32 + quad * 8];
            #pragma unroll
            for (int ct2 = 0; ct2 < 4; ++ct2) {
                const bf16x8 bv = *(const bf16x8*)&Vs[cur][(ct2 * 16 + l16) * 64 + ((kc * 32 + quad * 8) ^ swm)];
                accO[ct2] = mfma16(af, bv, accO[ct2]);
            }
        }
        cur ^= 1;
    }

    // one cross-lane sum reduction at the end (lanes with same quad hold same rows)
    float inv[4];
    #pragma unroll
    for (int r = 0; r < 4; ++r) {
        float s = lsum[r];
        #pragma unroll
        for (int o = 1; o < 16; o <<= 1) s += __shfl_xor(s, o);
        inv[r] = 1.0f / s;
    }
    #pragma unroll
    for (int ct2 = 0; ct2 < 4; ++ct2)
        #pragma unroll
        for (int r = 0; r < 4; ++r) {
            const int row = qt * 64 + w * 16 + quad * 4 + r;
            CTX[(size_t)(b * 512 + row) * 768 + h * 64 + ct2 * 16 + l16] =
                (bf16)(accO[ct2][r] * inv[r]);
        }
}

// ---------------------------------------------------------------------------
__global__ __launch_bounds__(256)
void embed_ln_k(const int* __restrict__ ids, const int* __restrict__ tts,
                const float* __restrict__ we, const float* __restrict__ pe,
                const float* __restrict__ te, const float* __restrict__ g,
                const float* __restrict__ b, float* __restrict__ X,
                bf16* __restrict__ XB)
{
    __shared__ float red[4];
    const int row = blockIdx.x;
    const int s   = row & 511;
    const int tid = threadIdx.x;
    const int id  = ids[row];
    const int tt  = tts[row];
    const float* pwp = we + (size_t)id * 768;
    const float* pt = te + (size_t)tt * 768;
    const float* pp = pe + (size_t)s * 768;
    const size_t base = (size_t)row * 768;

    float v[3];
    #pragma unroll
    for (int j = 0; j < 3; ++j) {
        const int c = tid + j * 256;
        v[j] = pwp[c] + pt[c] + pp[c];
    }
    float sm = v[0] + v[1] + v[2];
    for (int o = 32; o; o >>= 1) sm += __shfl_down(sm, o);
    if ((tid & 63) == 0) red[tid >> 6] = sm;
    __syncthreads();
    const float mu = (red[0] + red[1] + red[2] + red[3]) * (1.0f / 768.0f);
    float q = 0.f;
    #pragma unroll
    for (int j = 0; j < 3; ++j) { const float d = v[j] - mu; q += d * d; }
    __syncthreads();
    for (int o = 32; o; o >>= 1) q += __shfl_down(q, o);
    if ((tid & 63) == 0) red[tid >> 6] = q;
    __syncthreads();
    const float var  = (red[0] + red[1] + red[2] + red[3]) * (1.0f / 768.0f);
    const float rstd = rsqrtf(var + 1e-12f);
    #pragma unroll
    for (int j = 0; j < 3; ++j) {
        const int c = tid + j * 256;
        const float o = (v[j] - mu) * rstd * g[c] + b[c];
        X[base + c]  = o;
        XB[base + c] = (bf16)o;
    }
}

// T2: optional second fp32 partial (split-K GEMM) summed in during load.
__global__ __launch_bounds__(256)
void ln_k(const float* T, const float* T2, const float* res,
          const float* g, const float* bta,
          float* Xo, bf16* XBo)
{
    __shared__ float red[4];
    const int row = blockIdx.x;
    const int tid = threadIdx.x;
    const size_t base = (size_t)row * 768;

    float v[3];
    #pragma unroll
    for (int j = 0; j < 3; ++j) {
        const int c = tid + j * 256;
        float x = T[base + c];
        if (T2)  x += T2[base + c];
        if (res) x += res[base + c];
        v[j] = x;
    }
    float sm = v[0] + v[1] + v[2];
    for (int o = 32; o; o >>= 1) sm += __shfl_down(sm, o);
    if ((tid & 63) == 0) red[tid >> 6] = sm;
    __syncthreads();
    const float mu = (red[0] + red[1] + red[2] + red[3]) * (1.0f / 768.0f);
    float q = 0.f;
    #pragma unroll
    for (int j = 0; j < 3; ++j) { const float d = v[j] - mu; q += d * d; }
    __syncthreads();
    for (int o = 32; o; o >>= 1) q += __shfl_down(q, o);
    if ((tid & 63) == 0) red[tid >> 6] = q;
    __syncthreads();
    const float var  = (red[0] + red[1] + red[2] + red[3]) * (1.0f / 768.0f);
    const float rstd = rsqrtf(var + 1e-5f);
    #pragma unroll
    for (int j = 0; j < 3; ++j) {
        const int c = tid + j * 256;
        const float o = (v[j] - mu) * rstd * g[c] + bta[c];
        Xo[base + c]  = o;
        XBo[base + c] = (bf16)o;
    }
}

// ---------------------------------------------------------------------------
extern "C" void kernel_launch(void* const* d_in, const int* in_sizes, int n_in,
                              void* d_out, int out_size, void* d_ws, size_t ws_size,
                              hipStream_t stream)
{
    const int*   ids  = (const int*)d_in[0];
    const int*   tts  = (const int*)d_in[1];
    const float* mask = (const float*)d_in[2];
    const float* wemb = (const float*)d_in[3];
    const float* pemb = (const float*)d_in[4];
    const float* temb = (const float*)d_in[5];
    const float* eg   = (const float*)d_in[6];
    const float* eb   = (const float*)d_in[7];
    const float* Wq   = (const float*)d_in[8];
    const float* bq   = (const float*)d_in[9];
    const float* Wk   = (const float*)d_in[10];
    const float* bk   = (const float*)d_in[11];
    const float* Wv   = (const float*)d_in[12];
    const float* bv   = (const float*)d_in[13];
    const float* Wo   = (const float*)d_in[14];
    const float* bo   = (const float*)d_in[15];
    const float* ag   = (const float*)d_in[16];
    const float* ab   = (const float*)d_in[17];
    const float* W1   = (const float*)d_in[18];
    const float* b1   = (const float*)d_in[19];
    const float* W2   = (const float*)d_in[20];
    const float* b2   = (const float*)d_in[21];
    const float* fg   = (const float*)d_in[22];
    const float* fb   = (const float*)d_in[23];

    char* p = (char*)d_ws;
    float* X   = (float*)p; p += 12582912;   // residual stream fp32
    bf16* XB   = (bf16*)p;  p += 6291456;    // bf16 of current GEMM input
    bf16* Qb   = (bf16*)p;  p += 6291456;
    bf16* Kbuf = (bf16*)p;  p += 6291456;
    bf16* CTXb = (bf16*)p;  p += 6291456;
    float* T1  = (float*)p; p += 12582912;   // fp32 GEMM out (pre-LN)
    bf16* HB   = (bf16*)p;  p += 25165824;   // FFN hidden (B,S,F) bf16
    bf16* WB   = (bf16*)p;  p += 169869312;  // all-layer bf16 weights
    bf16* VT   = HB;                         // (B,H,64,S) — lifetime disjoint from HB
    float* T1b = (float*)Qb;                 // split-K kz=1 partial: Qb+Kbuf
                                             // (12.58 MB = M*N fp32), dead during
                                             // attn-out and FFN2 GEMMs

    embed_ln_k<<<4096, 256, 0, stream>>>(ids, tts, wemb, pemb, temb, eg, eb, X, XB);

    const size_t wdd = 589824, wdf = 2359296;
    for (int l = 0; l < 12; ++l) {
        bf16* wb = WB + (size_t)l * 7077888;
        cvt_layer<<<6912, 256, 0, stream>>>(
            Wq + l * wdd, Wk + l * wdd, Wv + l * wdd, Wo + l * wdd,
            W1 + l * wdf, W2 + l * wdf, wb);
        gemm_bt<2, 128, 1><<<dim3(18, 32), 256, 0, stream>>>(
            XB, wb, bq + l * 768, bk + l * 768, bv + l * 768,
            nullptr, nullptr, Qb, Kbuf, VT, 4096, 2304, 768);
        attn3<<<dim3(8, 12, 8), 256, 0, stream>>>(Qb, Kbuf, VT, mask, CTXb);
        // split-K=2: kz=0 (+bias) -> T1, kz=1 -> T1b; summed in ln_k
        gemm_bt<0, 64, 2><<<dim3(12, 32, 2), 256, 0, stream>>>(
            CTXb, wb + 1769472, bo + l * 768, nullptr, nullptr,
            T1, T1b, nullptr, nullptr, nullptr, 4096, 768, 768);
        ln_k<<<4096, 256, 0, stream>>>(T1, T1b, X, ag + l * 768, ab + l * 768, X, XB);
        gemm_bt<1, 128, 1><<<dim3(24, 32), 256, 0, stream>>>(
            XB, wb + 2359296, b1 + (size_t)l * 3072, nullptr, nullptr,
            nullptr, nullptr, HB, nullptr, nullptr, 4096, 3072, 768);
        gemm_bt<0, 64, 2><<<dim3(12, 32, 2), 256, 0, stream>>>(
            HB, wb + 4718592, b2 + l * 768, nullptr, nullptr,
            T1, T1b, nullptr, nullptr, nullptr, 4096, 768, 3072);
        float* outX = (l == 11) ? (float*)d_out : X;
        ln_k<<<4096, 256, 0, stream>>>(T1, T1b, nullptr, fg + l * 768, fb + l * 768, outX, XB);
    }
}